// Round 1
// baseline (253.781 us; speedup 1.0000x reference)
//
#include <hip/hip_runtime.h>

// SpriteAssembler via MFMA, operand-swapped: per 16-pixel tile,
//   ACC[64i][16px] = W[64i][64k] x B[64k][16px]   (f16 in, f32 acc)
// where W[i][j] = tanh(relu(d_j - d_i)) (A-operand, built once per wave),
//       B[j][px] = log2(1 - s[px][j])   (rebuilt per tile).
// masks = exp2(ACC) * clamp(s[px][i]) row-normalized (+eps).
// D layout gives each lane 4 contiguous i per accumulator -> float4 stores,
// and the i-reduction needs only 2 shfl_xor (over q-groups).

typedef __attribute__((ext_vector_type(8))) _Float16 half8;
typedef __attribute__((ext_vector_type(4))) float floatx4;

#define EPSF 1e-6f

__device__ inline float fast_exp2(float x){ return __builtin_amdgcn_exp2f(x); }
__device__ inline float fast_log2(float x){ return __builtin_amdgcn_logf(x); }  // log2
__device__ inline float fast_rcp (float x){ return __builtin_amdgcn_rcpf(x); }

__global__ __launch_bounds__(256, 2) void sprite_mfma_kernel(
    const float* __restrict__ shapes,   // [8, 65536, 64]
    const float* __restrict__ depths,   // [8, 64]
    float* __restrict__ out)            // [8, 65536, 64]
{
    const int wave  = threadIdx.x >> 6;
    const int lane  = threadIdx.x & 63;
    const int batch = blockIdx.x >> 8;   // 256 blocks per batch
    const int rblk  = blockIdx.x & 255;
    const int wid   = rblk * 4 + wave;   // wave id within batch [0,1024), 64 px each

    __shared__ float dsh[64];
    if (threadIdx.x < 64) dsh[threadIdx.x] = depths[batch * 64 + threadIdx.x];
    __syncthreads();

    const int c = lane & 15;   // A: m(i). B: n(px). D: col(px)
    const int q = lane >> 4;   // k-quad / D row group

    // ---- W fragments (A-operand), built once per wave ----
    // Aw[it][kt][e] = w[i][j] = tanh(relu(d_j - d_i)), i = it*16+c, j = kt*32+q*8+e
    half8 Aw[4][2];
    #pragma unroll
    for (int it = 0; it < 4; ++it) {
        float di = dsh[it * 16 + c];
        #pragma unroll
        for (int kt = 0; kt < 2; ++kt) {
            half8 h;
            #pragma unroll
            for (int jj = 0; jj < 8; ++jj) {
                int j = kt * 32 + q * 8 + jj;
                float x = fmaxf(dsh[j] - di, 0.0f);            // relu(d_j - d_i)
                float e = fast_exp2(x * 2.885390082f);         // e^{2x}
                h[jj] = (_Float16)((e - 1.0f) * fast_rcp(e + 1.0f));  // tanh
            }
            Aw[it][kt] = h;
        }
    }

    const long pxbase = (long)batch * 65536 + (long)wid * 64;
    const float* sp = shapes + (pxbase + c) * 64;   // this lane's px row (tile 0)
    float* op = out + (pxbase + c) * 64;

    // B-layout loads: lane reads s[px=c][q*8 .. q*8+7] and the +32 block.
    float4 pf0 = *(const float4*)(sp + q * 8);
    float4 pf1 = *(const float4*)(sp + q * 8 + 4);
    float4 pf2 = *(const float4*)(sp + q * 8 + 32);
    float4 pf3 = *(const float4*)(sp + q * 8 + 36);

    for (int tile = 0; tile < 4; ++tile) {
        const float* srow = sp + tile * 16 * 64;

        float4 s0 = pf0, s1 = pf1, s2 = pf2, s3 = pf3;
        if (tile < 3) {                          // software prefetch next tile
            const float* sn = srow + 16 * 64 + q * 8;
            pf0 = *(const float4*)(sn);
            pf1 = *(const float4*)(sn + 4);
            pf2 = *(const float4*)(sn + 32);
            pf3 = *(const float4*)(sn + 36);
        }

        // epilogue gather of raw s at the D layout (same lines -> L1/L2 hits)
        float4 sg[4];
        #pragma unroll
        for (int it = 0; it < 4; ++it)
            sg[it] = *(const float4*)(srow + it * 16 + q * 4);

        float sv[16] = {s0.x, s0.y, s0.z, s0.w, s1.x, s1.y, s1.z, s1.w,
                        s2.x, s2.y, s2.z, s2.w, s3.x, s3.y, s3.z, s3.w};
        half8 B_lo, B_hi;                       // B[j][px=c] = log2(1 - s)
        #pragma unroll
        for (int e = 0; e < 8; ++e) {
            float slo = fminf(fmaxf(sv[e],     EPSF), 1.0f - EPSF);
            float shi = fminf(fmaxf(sv[8 + e], EPSF), 1.0f - EPSF);
            B_lo[e] = (_Float16)fast_log2(1.0f - slo);
            B_hi[e] = (_Float16)fast_log2(1.0f - shi);
        }

        floatx4 acc[4];
        #pragma unroll
        for (int it = 0; it < 4; ++it) {
            floatx4 a = {0.f, 0.f, 0.f, 0.f};
            a = __builtin_amdgcn_mfma_f32_16x16x32_f16(Aw[it][0], B_lo, a, 0, 0, 0);
            a = __builtin_amdgcn_mfma_f32_16x16x32_f16(Aw[it][1], B_hi, a, 0, 0, 0);
            acc[it] = a;
        }

        // D layout: value (it, r) is ACC[i = it*16 + q*4 + r][px = tile*16 + c]
        // u = exp2(acc) * clamp(s)   (identity K-half folded into f32 multiply)
        float u[4][4];
        float tot = 0.f;
        #pragma unroll
        for (int it = 0; it < 4; ++it) {
            #pragma unroll
            for (int r = 0; r < 4; ++r) {
                float s = fminf(fmaxf(sg[it][r], EPSF), 1.0f - EPSF);
                float v = fast_exp2(acc[it][r]) * s;
                u[it][r] = v;
                tot += v;
            }
        }
        tot += __shfl_xor(tot, 16, 64);          // reduce over q-groups (all 64 i)
        tot += __shfl_xor(tot, 32, 64);
        float inv = fast_rcp(tot + EPSF);

        float* orow = op + tile * 16 * 64;
        #pragma unroll
        for (int it = 0; it < 4; ++it) {
            float4 o = {u[it][0] * inv, u[it][1] * inv,
                        u[it][2] * inv, u[it][3] * inv};
            *(float4*)(orow + it * 16 + q * 4) = o;
        }
    }
}

extern "C" void kernel_launch(void* const* d_in, const int* in_sizes, int n_in,
                              void* d_out, int out_size, void* d_ws, size_t ws_size,
                              hipStream_t stream) {
    const float* shapes = (const float*)d_in[0];
    const float* depths = (const float*)d_in[1];
    float* out = (float*)d_out;
    // 8 batches * 256 blocks, 256 threads (4 waves), 64 px per wave
    sprite_mfma_kernel<<<2048, 256, 0, stream>>>(shapes, depths, out);
}

// Round 2
// 248.546 us; speedup vs baseline: 1.0211x; 1.0211x over previous
//
#include <hip/hip_runtime.h>

// SpriteAssembler via MFMA, operand-swapped, identity-folded:
//   ACC[64i][16px] = W'[64i][64k] x B[64k][16px]   (f16 in, f32 acc)
// W part:   W[i][j] = tanh(relu(d_j - d_i)),  B[j][px] = log2(1 - s[px][j])
// id part:  acc[it] += Id x log2(s)  -- one extra MFMA per 16-row i-tile
//           (identity overlaps exactly one 32-wide k-tile), so log2(s) rides
//           the same MFMA instead of a second gather stream.
// masks = exp2(ACC) row-normalized (+eps).
// D layout: lane holds 4 contiguous i per acc -> float4 stores, 2-shfl reduce.

typedef __attribute__((ext_vector_type(8))) _Float16 half8;
typedef __attribute__((ext_vector_type(4))) float floatx4;

#define EPSF 1e-6f

__device__ inline float fast_exp2(float x){ return __builtin_amdgcn_exp2f(x); }
__device__ inline float fast_log2(float x){ return __builtin_amdgcn_logf(x); }  // log2
__device__ inline float fast_rcp (float x){ return __builtin_amdgcn_rcpf(x); }

__global__ __launch_bounds__(256, 2) void sprite_mfma_kernel(
    const float* __restrict__ shapes,   // [8, 65536, 64]
    const float* __restrict__ depths,   // [8, 64]
    float* __restrict__ out)            // [8, 65536, 64]
{
    const int wave  = threadIdx.x >> 6;
    const int lane  = threadIdx.x & 63;
    const int batch = blockIdx.x >> 7;   // 128 blocks per batch
    const int rblk  = blockIdx.x & 127;
    const int wid   = rblk * 4 + wave;   // wave id within batch [0,512), 128 px each

    __shared__ float dsh[64];
    if (threadIdx.x < 64) dsh[threadIdx.x] = depths[batch * 64 + threadIdx.x];
    __syncthreads();

    const int c = lane & 15;   // A: m(i-local). B: n(px). D: col(px)
    const int q = lane >> 4;   // k-quad / D row group

    // ---- W fragments (A-operand), built once per wave, amortized over 128 px ----
    // Aw[it][kt][e] = w[i][j] = tanh(relu(d_j - d_i)), i = it*16+c, j = kt*32+q*8+e
    half8 Aw[4][2];
    #pragma unroll
    for (int it = 0; it < 4; ++it) {
        float di = dsh[it * 16 + c];
        #pragma unroll
        for (int kt = 0; kt < 2; ++kt) {
            half8 h;
            #pragma unroll
            for (int jj = 0; jj < 8; ++jj) {
                int j = kt * 32 + q * 8 + jj;
                float x = fmaxf(dsh[j] - di, 0.0f);            // relu(d_j - d_i)
                float e = fast_exp2(x * 2.885390082f);         // e^{2x}
                h[jj] = (_Float16)((e - 1.0f) * fast_rcp(e + 1.0f));  // tanh
            }
            Aw[it][kt] = h;
        }
    }

    // identity A-fragments: A_id[m][k_local] = 1 iff k_local == (it&1)*16 + m
    half8 idlo, idhi;
    #pragma unroll
    for (int jj = 0; jj < 8; ++jj) {
        idlo[jj] = (q * 8 + jj == c)      ? (_Float16)1.0f : (_Float16)0.0f;
        idhi[jj] = (q * 8 + jj == 16 + c) ? (_Float16)1.0f : (_Float16)0.0f;
    }

    const long pxbase = (long)batch * 65536 + (long)wid * 128;
    const float* sp = shapes + (pxbase + c) * 64;   // this lane's px row (tile 0)
    float* op = out + (pxbase + c) * 64;

    // B-layout loads: lane reads s[px=c][q*8 .. q*8+7] and the +32 block.
    float4 pf0 = *(const float4*)(sp + q * 8);
    float4 pf1 = *(const float4*)(sp + q * 8 + 4);
    float4 pf2 = *(const float4*)(sp + q * 8 + 32);
    float4 pf3 = *(const float4*)(sp + q * 8 + 36);

    for (int tile = 0; tile < 8; ++tile) {
        float4 s0 = pf0, s1 = pf1, s2 = pf2, s3 = pf3;
        if (tile < 7) {                          // software prefetch next tile
            const float* sn = sp + (tile + 1) * 16 * 64 + q * 8;
            pf0 = *(const float4*)(sn);
            pf1 = *(const float4*)(sn + 4);
            pf2 = *(const float4*)(sn + 32);
            pf3 = *(const float4*)(sn + 36);
        }

        float sv[16] = {s0.x, s0.y, s0.z, s0.w, s1.x, s1.y, s1.z, s1.w,
                        s2.x, s2.y, s2.z, s2.w, s3.x, s3.y, s3.z, s3.w};
        half8 B_lo, B_hi;                        // B[j][px=c]  = log2(1 - s)
        half8 C_lo, C_hi;                        // B2[j][px=c] = log2(s)
        #pragma unroll
        for (int e = 0; e < 8; ++e) {
            float slo = fminf(fmaxf(sv[e],     EPSF), 1.0f - EPSF);
            float shi = fminf(fmaxf(sv[8 + e], EPSF), 1.0f - EPSF);
            B_lo[e] = (_Float16)fast_log2(1.0f - slo);
            B_hi[e] = (_Float16)fast_log2(1.0f - shi);
            C_lo[e] = (_Float16)fast_log2(slo);
            C_hi[e] = (_Float16)fast_log2(shi);
        }

        floatx4 acc[4];
        #pragma unroll
        for (int it = 0; it < 4; ++it) {
            floatx4 a = {0.f, 0.f, 0.f, 0.f};
            a = __builtin_amdgcn_mfma_f32_16x16x32_f16(Aw[it][0], B_lo, a, 0, 0, 0);
            a = __builtin_amdgcn_mfma_f32_16x16x32_f16(Aw[it][1], B_hi, a, 0, 0, 0);
            // identity part: k-tile (it>>1), offset parity (it&1)
            a = __builtin_amdgcn_mfma_f32_16x16x32_f16(
                    (it & 1) ? idhi : idlo, (it < 2) ? C_lo : C_hi, a, 0, 0, 0);
            acc[it] = a;
        }

        // D layout: value (it, r) is ACC[i = it*16 + q*4 + r][px = tile*16 + c]
        float u[4][4];
        float tot = 0.f;
        #pragma unroll
        for (int it = 0; it < 4; ++it) {
            #pragma unroll
            for (int r = 0; r < 4; ++r) {
                float v = fast_exp2(acc[it][r]);
                u[it][r] = v;
                tot += v;
            }
        }
        tot += __shfl_xor(tot, 16, 64);          // reduce over q-groups (all 64 i)
        tot += __shfl_xor(tot, 32, 64);
        float inv = fast_rcp(tot + EPSF);

        float* orow = op + tile * 16 * 64;
        #pragma unroll
        for (int it = 0; it < 4; ++it) {
            float4 o = {u[it][0] * inv, u[it][1] * inv,
                        u[it][2] * inv, u[it][3] * inv};
            *(float4*)(orow + it * 16 + q * 4) = o;
        }
    }
}

extern "C" void kernel_launch(void* const* d_in, const int* in_sizes, int n_in,
                              void* d_out, int out_size, void* d_ws, size_t ws_size,
                              hipStream_t stream) {
    const float* shapes = (const float*)d_in[0];
    const float* depths = (const float*)d_in[1];
    float* out = (float*)d_out;
    // 8 batches * 128 blocks, 256 threads (4 waves), 128 px per wave
    sprite_mfma_kernel<<<1024, 256, 0, stream>>>(shapes, depths, out);
}

// Round 3
// 245.620 us; speedup vs baseline: 1.0332x; 1.0119x over previous
//
#include <hip/hip_runtime.h>

// SpriteAssembler via MFMA, operand-swapped, identity-folded:
//   ACC[64i][16px] = W'[64i][64k] x B[64k][16px]   (f16 in, f32 acc)
// W part:   W[i][j] = tanh(relu(d_j - d_i)),  B[j][px] = log2(1 - s[px][j])
// id part:  acc[it] += Id x log2(s)  -- one extra MFMA per 16-row i-tile.
// masks = exp2(ACC) row-normalized (+eps).
// R3: 512-thread blocks (8 waves) x 64 px/wave -> 32 waves/CU nominal (2x R2),
//     inner loop identical to R2; nontemporal stores (output never re-read).

typedef __attribute__((ext_vector_type(8))) _Float16 half8;
typedef __attribute__((ext_vector_type(4))) float floatx4;

#define EPSF 1e-6f

__device__ inline float fast_exp2(float x){ return __builtin_amdgcn_exp2f(x); }
__device__ inline float fast_log2(float x){ return __builtin_amdgcn_logf(x); }  // log2
__device__ inline float fast_rcp (float x){ return __builtin_amdgcn_rcpf(x); }

__global__ __launch_bounds__(512, 4) void sprite_mfma_kernel(
    const float* __restrict__ shapes,   // [8, 65536, 64]
    const float* __restrict__ depths,   // [8, 64]
    float* __restrict__ out)            // [8, 65536, 64]
{
    const int wave  = threadIdx.x >> 6;  // [0,8)
    const int lane  = threadIdx.x & 63;
    const int batch = blockIdx.x >> 7;   // 128 blocks per batch
    const int rblk  = blockIdx.x & 127;
    const int wid   = rblk * 8 + wave;   // wave id within batch [0,1024), 64 px each

    __shared__ float dsh[64];
    if (threadIdx.x < 64) dsh[threadIdx.x] = depths[batch * 64 + threadIdx.x];
    __syncthreads();

    const int c = lane & 15;   // A: m(i-local). B: n(px). D: col(px)
    const int q = lane >> 4;   // k-quad / D row group

    // ---- W fragments (A-operand), built once per wave ----
    // Aw[it][kt][e] = w[i][j] = tanh(relu(d_j - d_i)), i = it*16+c, j = kt*32+q*8+e
    half8 Aw[4][2];
    #pragma unroll
    for (int it = 0; it < 4; ++it) {
        float di = dsh[it * 16 + c];
        #pragma unroll
        for (int kt = 0; kt < 2; ++kt) {
            half8 h;
            #pragma unroll
            for (int jj = 0; jj < 8; ++jj) {
                int j = kt * 32 + q * 8 + jj;
                float x = fmaxf(dsh[j] - di, 0.0f);            // relu(d_j - d_i)
                float e = fast_exp2(x * 2.885390082f);         // e^{2x}
                h[jj] = (_Float16)((e - 1.0f) * fast_rcp(e + 1.0f));  // tanh
            }
            Aw[it][kt] = h;
        }
    }

    // identity A-fragments: nonzero only where k_local == (it&1)*16 + m
    half8 idlo, idhi;
    #pragma unroll
    for (int jj = 0; jj < 8; ++jj) {
        idlo[jj] = (q * 8 + jj == c)      ? (_Float16)1.0f : (_Float16)0.0f;
        idhi[jj] = (q * 8 + jj == 16 + c) ? (_Float16)1.0f : (_Float16)0.0f;
    }

    const long pxbase = (long)batch * 65536 + (long)wid * 64;
    const float* sp = shapes + (pxbase + c) * 64;   // this lane's px row (tile 0)
    float* op = out + (pxbase + c) * 64;

    // B-layout loads: lane reads s[px=c][q*8 .. q*8+7] and the +32 block.
    float4 pf0 = *(const float4*)(sp + q * 8);
    float4 pf1 = *(const float4*)(sp + q * 8 + 4);
    float4 pf2 = *(const float4*)(sp + q * 8 + 32);
    float4 pf3 = *(const float4*)(sp + q * 8 + 36);

    for (int tile = 0; tile < 4; ++tile) {
        float4 s0 = pf0, s1 = pf1, s2 = pf2, s3 = pf3;
        if (tile < 3) {                          // software prefetch next tile
            const float* sn = sp + (tile + 1) * 16 * 64 + q * 8;
            pf0 = *(const float4*)(sn);
            pf1 = *(const float4*)(sn + 4);
            pf2 = *(const float4*)(sn + 32);
            pf3 = *(const float4*)(sn + 36);
        }

        float sv[16] = {s0.x, s0.y, s0.z, s0.w, s1.x, s1.y, s1.z, s1.w,
                        s2.x, s2.y, s2.z, s2.w, s3.x, s3.y, s3.z, s3.w};
        half8 B_lo, B_hi;                        // B[j][px=c]  = log2(1 - s)
        half8 C_lo, C_hi;                        // B2[j][px=c] = log2(s)
        #pragma unroll
        for (int e = 0; e < 8; ++e) {
            float slo = fminf(fmaxf(sv[e],     EPSF), 1.0f - EPSF);
            float shi = fminf(fmaxf(sv[8 + e], EPSF), 1.0f - EPSF);
            B_lo[e] = (_Float16)fast_log2(1.0f - slo);
            B_hi[e] = (_Float16)fast_log2(1.0f - shi);
            C_lo[e] = (_Float16)fast_log2(slo);
            C_hi[e] = (_Float16)fast_log2(shi);
        }

        floatx4 acc[4];
        #pragma unroll
        for (int it = 0; it < 4; ++it) {
            floatx4 a = {0.f, 0.f, 0.f, 0.f};
            a = __builtin_amdgcn_mfma_f32_16x16x32_f16(Aw[it][0], B_lo, a, 0, 0, 0);
            a = __builtin_amdgcn_mfma_f32_16x16x32_f16(Aw[it][1], B_hi, a, 0, 0, 0);
            a = __builtin_amdgcn_mfma_f32_16x16x32_f16(
                    (it & 1) ? idhi : idlo, (it < 2) ? C_lo : C_hi, a, 0, 0, 0);
            acc[it] = a;
        }

        // D layout: value (it, r) is ACC[i = it*16 + q*4 + r][px = tile*16 + c]
        float u[4][4];
        float tot = 0.f;
        #pragma unroll
        for (int it = 0; it < 4; ++it) {
            #pragma unroll
            for (int r = 0; r < 4; ++r) {
                float v = fast_exp2(acc[it][r]);
                u[it][r] = v;
                tot += v;
            }
        }
        tot += __shfl_xor(tot, 16, 64);          // reduce over q-groups (all 64 i)
        tot += __shfl_xor(tot, 32, 64);
        float inv = fast_rcp(tot + EPSF);

        float* orow = op + tile * 16 * 64;
        #pragma unroll
        for (int it = 0; it < 4; ++it) {
            floatx4 o = {u[it][0] * inv, u[it][1] * inv,
                         u[it][2] * inv, u[it][3] * inv};
            __builtin_nontemporal_store(o, (floatx4*)(orow + it * 16 + q * 4));
        }
    }
}

extern "C" void kernel_launch(void* const* d_in, const int* in_sizes, int n_in,
                              void* d_out, int out_size, void* d_ws, size_t ws_size,
                              hipStream_t stream) {
    const float* shapes = (const float*)d_in[0];
    const float* depths = (const float*)d_in[1];
    float* out = (float*)d_out;
    // 8 batches * 128 blocks, 512 threads (8 waves), 64 px per wave
    sprite_mfma_kernel<<<1024, 512, 0, stream>>>(shapes, depths, out);
}